// Round 5
// baseline (476.688 us; speedup 1.0000x reference)
//
#include <hip/hip_runtime.h>

#define QK_SCALE 0.17677669529663687f

typedef __attribute__((ext_vector_type(8))) short bf16x8;
typedef __attribute__((ext_vector_type(4))) short bf16x4;
typedef __attribute__((ext_vector_type(2))) short bf16x2;
typedef __attribute__((ext_vector_type(4))) float floatx4;

__device__ __forceinline__ unsigned short f2bf(float f) {
    unsigned int u = __float_as_uint(f);
    u += 0x7fffu + ((u >> 16) & 1u);   // round-to-nearest-even
    return (unsigned short)(u >> 16);
}

__device__ __forceinline__ bf16x8 ld8_2x4(const short* p) {  // 8B-aligned pair load
    union { bf16x8 v8; bf16x4 v4[2]; } u;
    u.v4[0] = *(const bf16x4*)p;
    u.v4[1] = *(const bf16x4*)(p + 4);
    return u.v8;
}

__device__ __forceinline__ bf16x8 ld8_4x2(const short* p) {  // 4B-aligned quad load
    union { bf16x8 v8; bf16x2 v2[4]; } u;
    u.v2[0] = *(const bf16x2*)p;
    u.v2[1] = *(const bf16x2*)(p + 2);
    u.v2[2] = *(const bf16x2*)(p + 4);
    u.v2[3] = *(const bf16x2*)(p + 6);
    return u.v8;
}

// ---- prep: bf16 weights + combined (mask + gathered rel-pos bias) table ----
// ws layout: [0, 131072) bytes: qkv_w bf16 (49152 sh) then proj_w bf16 (16384 sh)
//            [131072, ...): cm2 fp32 tiled [w][h][row<49][lid<16][nt<4] = 3,211,264 B
//            cm2 cols nt*16+lid >= 49 hold -1e30 (softmax pad baked in)
__global__ __launch_bounds__(256) void prep_kernel(
    const float* __restrict__ qkv_w, const float* __restrict__ proj_w,
    const float* __restrict__ bias_table, const float* __restrict__ mask,
    unsigned short* __restrict__ wbf, float* __restrict__ cm2)
{
    int g = blockIdx.x * 256 + threadIdx.x;
    if (g < 49152) {
        wbf[g] = f2bf(qkv_w[g]);
    } else if (g < 65536) {
        wbf[g] = f2bf(proj_w[g - 49152]);
    } else if (g < 868352) {
        int t = g - 65536;              // ((((w*4+h)*49 + row)*16 + lid)*4 + nt)
        int nt  = t & 3;
        int lid = (t >> 2) & 15;
        int t2  = t >> 6;               // (w*4+h)*49 + row
        int row = t2 % 49;
        int wh  = t2 / 49;
        int h   = wh & 3;
        int w   = wh >> 2;
        int col = nt * 16 + lid;
        float v;
        if (col < 49) {
            int idx = (row / 7 - col / 7 + 6) * 13 + (row % 7 - col % 7 + 6);
            v = mask[w * 2401 + row * 49 + col] + bias_table[idx * 4 + h];
        } else {
            v = -1e30f;
        }
        cm2[t] = v;
    }
}

// 512 threads = 8 waves; wave = (h = wid>>1, half = wid&1). Each head owned by a
// wave PAIR: QKV col-tiles j (one q, one k, one v tile of 16 cols each);
// S/softmax/PV/proj rows mt in {2half, 2half+1}.
//
// LDS map (shorts). Head h region base hq = h*6528 (13056 B):
//   q:  hq+0     64 rows x 34  (2176)     [dead after S frag loads — see barrier]
//   k:  hq+2176  64 rows x 34  (2176)     [dead after S frag loads]
//   vT: hq+4352  32 rows x 68  (2176)
//   P:  hq+0     64 rows x 68  (4352)     [overlaps dead q+k exactly; RACE NOTE:
//       q/k are shared by the wave PAIR, so a barrier must separate the pair's
//       aq/bk ds_reads from P-writes — placed right after the S MFMAs]
// xs/ao: offset 0, 64 rows x 136 (8704)   [time-sliced vs head regions, barriers]
// total 26112 shorts = 52224 B -> 3 blocks/CU = 24 waves/CU (6 waves/SIMD)
__global__ __launch_bounds__(512, 6) void winattn_mfma(
    const float* __restrict__ x,
    const float* __restrict__ qkv_b,
    const float* __restrict__ proj_b,
    const unsigned short* __restrict__ wbf,
    const float* __restrict__ cm2,
    float* __restrict__ out)
{
    __shared__ __align__(16) short smem[26112];   // 52224 B

    const int tid  = threadIdx.x;
    const int lane = tid & 63;
    const int lid  = lane & 15;
    const int quad = lane >> 4;
    const int wid  = tid >> 6;        // 0..7
    const int h    = wid >> 1;        // head
    const int half = wid & 1;         // row-half / col-subtile owner
    const int b    = blockIdx.x;
    const int w    = b & 63;
    const int hq   = h * 6528;

    // ---- Phase 0: stage x (49x128) fp32 -> bf16 LDS rows (pitch 136), pad rows zeroed ----
    {
        const float4* xg = (const float4*)(x + (size_t)b * 6272);
        for (int i = tid; i < 1568; i += 512) {       // 49*32 float4s
            int n = i >> 5, c4 = i & 31;
            float4 v = xg[i];
            ushort4 u;
            u.x = f2bf(v.x); u.y = f2bf(v.y); u.z = f2bf(v.z); u.w = f2bf(v.w);
            *(ushort4*)&smem[n * 136 + c4 * 4] = u;
        }
        ushort4 z; z.x = 0; z.y = 0; z.z = 0; z.w = 0;
        for (int i = tid; i < 510; i += 512)          // rows 49..63: 15*136/4 = 510
            *(ushort4*)&smem[49 * 136 + i * 4] = z;
    }
    __syncthreads();

    // ---- load full A tile (64x128) into registers: 16 frags ----
    bf16x8 ax[4][4];
    #pragma unroll
    for (int mt = 0; mt < 4; ++mt)
        #pragma unroll
        for (int kb = 0; kb < 4; ++kb)
            ax[mt][kb] = *(const bf16x8*)&smem[(mt * 16 + lid) * 136 + kb * 32 + quad * 8];
    __syncthreads();   // xs consumed; head regions may now be written

    const floatx4 z4 = {0.f, 0.f, 0.f, 0.f};

    // ---- QKV: wave (h,half) computes 3 col-tiles: one q, one k, one v ----
    #pragma unroll
    for (int j = 0; j < 3; ++j) {
        const int cb = j * 128 + h * 32 + half * 16;   // q/k/v col block
        const unsigned short* wr = wbf + (size_t)(cb + lid) * 128 + quad * 8;
        floatx4 acc[4] = {z4, z4, z4, z4};
        #pragma unroll
        for (int kb = 0; kb < 4; ++kb) {
            bf16x8 bw = *(const bf16x8*)(wr + kb * 32);
            #pragma unroll
            for (int mt = 0; mt < 4; ++mt)
                acc[mt] = __builtin_amdgcn_mfma_f32_16x16x32_bf16(ax[mt][kb], bw, acc[mt], 0, 0, 0);
        }
        const float bias = qkv_b[cb + lid];
        #pragma unroll
        for (int mt = 0; mt < 4; ++mt) {
            #pragma unroll
            for (int r = 0; r < 4; ++r) {
                const int row = mt * 16 + quad * 4 + r;
                const float v = acc[mt][r] + bias;
                if (j == 0) {         // q (pre-scaled), pitch 34, cols half*16..
                    smem[hq + row * 34 + half * 16 + lid] = (short)f2bf(v * QK_SCALE);
                } else if (j == 1) {  // k row-major, pitch 34
                    smem[hq + 2176 + row * 34 + half * 16 + lid] = (short)f2bf(v);
                } else {              // v transposed: vT[d][token], pitch 68
                    smem[hq + 4352 + (half * 16 + lid) * 68 + row] = (short)f2bf(v);
                }
            }
        }
    }
    __syncthreads();   // q/k cols + vT rows cross the wave pair

    // ---- prefetch cm2 slab for m=0 (L2 latency hides under S-phase) ----
    const float4* cm2b = (const float4*)cm2 + ((size_t)(w * 4 + h) * 49) * 16 + lid;
    float4 cmv[2][4];
    #pragma unroll
    for (int r = 0; r < 4; ++r) {
        const int row  = (2 * half) * 16 + quad * 4 + r;
        const int rowc = (row < 49) ? row : 48;
        cmv[0][r] = cm2b[rowc * 16];
    }

    // ---- S = q @ k^T : own 2 M-tiles x 4 N-tiles (8 MFMAs) ----
    bf16x8 aq[2], bk[4];
    #pragma unroll
    for (int m = 0; m < 2; ++m)
        aq[m] = ld8_4x2(&smem[hq + ((2 * half + m) * 16 + lid) * 34 + quad * 8]);
    #pragma unroll
    for (int nt = 0; nt < 4; ++nt)
        bk[nt] = ld8_4x2(&smem[hq + 2176 + (nt * 16 + lid) * 34 + quad * 8]);

    floatx4 sacc[2][4];
    #pragma unroll
    for (int m = 0; m < 2; ++m)
        #pragma unroll
        for (int nt = 0; nt < 4; ++nt)
            sacc[m][nt] = __builtin_amdgcn_mfma_f32_16x16x32_bf16(aq[m], bk[nt], z4, 0, 0, 0);

    // Both waves of the pair must finish their aq/bk ds_reads before either
    // overwrites q/k with P (P overlays q+k). Barrier here closes the race.
    __syncthreads();

    // ---- softmax in C-layout; write P (bf16, pitch 68) into dead q/k region ----
    // cm2 has -1e30 baked into cols >= 49, so no col clamp/select needed.
    float invs[2][4];
    #pragma unroll
    for (int m = 0; m < 2; ++m) {
        if (m < 1) {   // prefetch next slab while computing this one
            #pragma unroll
            for (int r = 0; r < 4; ++r) {
                const int row  = (2 * half + 1) * 16 + quad * 4 + r;
                const int rowc = (row < 49) ? row : 48;
                cmv[1][r] = cm2b[rowc * 16];
            }
        }
        #pragma unroll
        for (int r = 0; r < 4; ++r) {
            const int row = (2 * half + m) * 16 + quad * 4 + r;
            float sv[4];
            #pragma unroll
            for (int nt = 0; nt < 4; ++nt)
                sv[nt] = sacc[m][nt][r] + cmv[m][r][nt];
            float mx = fmaxf(fmaxf(sv[0], sv[1]), fmaxf(sv[2], sv[3]));
            #pragma unroll
            for (int d = 1; d < 16; d <<= 1) mx = fmaxf(mx, __shfl_xor(mx, d));
            float sum = 0.f;
            #pragma unroll
            for (int nt = 0; nt < 4; ++nt) { float p = __expf(sv[nt] - mx); sv[nt] = p; sum += p; }
            #pragma unroll
            for (int d = 1; d < 16; d <<= 1) sum += __shfl_xor(sum, d);
            invs[m][r] = 1.f / sum;
            #pragma unroll
            for (int nt = 0; nt < 4; ++nt)
                smem[hq + row * 68 + nt * 16 + lid] = (short)f2bf(sv[nt]);
        }
    }

    // ---- O = P @ v : own 2 M-tiles (8 MFMAs), scale rows by 1/sum ----
    bf16x8 bv[2][2];
    #pragma unroll
    for (int nt2 = 0; nt2 < 2; ++nt2)
        #pragma unroll
        for (int kb2 = 0; kb2 < 2; ++kb2)
            bv[nt2][kb2] = ld8_2x4(&smem[hq + 4352 + (nt2 * 16 + lid) * 68 + kb2 * 32 + quad * 8]);

    floatx4 oacc[2][2] = {{z4, z4}, {z4, z4}};
    #pragma unroll
    for (int m = 0; m < 2; ++m) {
        #pragma unroll
        for (int kb2 = 0; kb2 < 2; ++kb2) {
            bf16x8 ap = ld8_2x4(&smem[hq + ((2 * half + m) * 16 + lid) * 68 + kb2 * 32 + quad * 8]);
            #pragma unroll
            for (int nt2 = 0; nt2 < 2; ++nt2)
                oacc[m][nt2] = __builtin_amdgcn_mfma_f32_16x16x32_bf16(ap, bv[nt2][kb2], oacc[m][nt2], 0, 0, 0);
        }
    }

    __syncthreads();   // all O MFMAs done everywhere; P/vT/q/k dead -> ao may overwrite

    // ---- write attn-out (bf16) to ao (pitch 136, offset 0), own rows ----
    #pragma unroll
    for (int m = 0; m < 2; ++m)
        #pragma unroll
        for (int nt2 = 0; nt2 < 2; ++nt2)
            #pragma unroll
            for (int r = 0; r < 4; ++r) {
                const int row = (2 * half + m) * 16 + quad * 4 + r;
                smem[row * 136 + h * 32 + nt2 * 16 + lid] =
                    (short)f2bf(oacc[m][nt2][r] * invs[m][r]);
            }
    __syncthreads();

    // ---- proj: C2 = ao @ proj_w.T ; wave (h,half) -> cols [32h,32h+32) x own rows ----
    bf16x8 aa[2][4];
    #pragma unroll
    for (int m = 0; m < 2; ++m)
        #pragma unroll
        for (int kb = 0; kb < 4; ++kb)
            aa[m][kb] = *(const bf16x8*)&smem[((2 * half + m) * 16 + lid) * 136 + kb * 32 + quad * 8];

    float* outb = out + (size_t)b * 6272;
    #pragma unroll
    for (int nt = 0; nt < 2; ++nt) {
        const int cb = h * 32 + nt * 16;
        const unsigned short* wr = wbf + 49152 + (size_t)(cb + lid) * 128 + quad * 8;
        floatx4 acc[2] = {z4, z4};
        #pragma unroll
        for (int kb = 0; kb < 4; ++kb) {
            bf16x8 bw = *(const bf16x8*)(wr + kb * 32);
            #pragma unroll
            for (int m = 0; m < 2; ++m)
                acc[m] = __builtin_amdgcn_mfma_f32_16x16x32_bf16(aa[m][kb], bw, acc[m], 0, 0, 0);
        }
        const float pb = proj_b[cb + lid];
        #pragma unroll
        for (int m = 0; m < 2; ++m)
            #pragma unroll
            for (int r = 0; r < 4; ++r) {
                const int row = (2 * half + m) * 16 + quad * 4 + r;
                if (row < 49)
                    outb[row * 128 + cb + lid] = acc[m][r] + pb;
            }
    }
}

extern "C" void kernel_launch(void* const* d_in, const int* in_sizes, int n_in,
                              void* d_out, int out_size, void* d_ws, size_t ws_size,
                              hipStream_t stream) {
    (void)in_sizes; (void)n_in; (void)out_size; (void)ws_size;
    const float* x          = (const float*)d_in[0];
    const float* mask       = (const float*)d_in[1];
    const float* qkv_w      = (const float*)d_in[2];
    const float* qkv_b      = (const float*)d_in[3];
    const float* proj_w     = (const float*)d_in[4];
    const float* proj_b     = (const float*)d_in[5];
    const float* bias_table = (const float*)d_in[6];

    unsigned short* wbf = (unsigned short*)d_ws;                 // 131072 B
    float* cm2          = (float*)((char*)d_ws + 131072);        // 3,211,264 B

    prep_kernel<<<3392, 256, 0, stream>>>(qkv_w, proj_w, bias_table, mask, wbf, cm2);
    winattn_mfma<<<4096, 512, 0, stream>>>(x, qkv_b, proj_b, wbf, cm2, (float*)d_out);
}

// Round 7
// 311.729 us; speedup vs baseline: 1.5292x; 1.5292x over previous
//
#include <hip/hip_runtime.h>

#define QK_SCALE 0.17677669529663687f

typedef __attribute__((ext_vector_type(8))) short bf16x8;
typedef __attribute__((ext_vector_type(4))) short bf16x4;
typedef __attribute__((ext_vector_type(2))) short bf16x2;
typedef __attribute__((ext_vector_type(4))) float floatx4;

__device__ __forceinline__ unsigned short f2bf(float f) {
    unsigned int u = __float_as_uint(f);
    u += 0x7fffu + ((u >> 16) & 1u);   // round-to-nearest-even
    return (unsigned short)(u >> 16);
}

__device__ __forceinline__ bf16x8 ld8_2x4(const short* p) {  // 8B-aligned pair load
    union { bf16x8 v8; bf16x4 v4[2]; } u;
    u.v4[0] = *(const bf16x4*)p;
    u.v4[1] = *(const bf16x4*)(p + 4);
    return u.v8;
}

__device__ __forceinline__ bf16x8 ld8_4x2(const short* p) {  // 4B-aligned quad load
    union { bf16x8 v8; bf16x2 v2[4]; } u;
    u.v2[0] = *(const bf16x2*)p;
    u.v2[1] = *(const bf16x2*)(p + 2);
    u.v2[2] = *(const bf16x2*)(p + 4);
    u.v2[3] = *(const bf16x2*)(p + 6);
    return u.v8;
}

// ---- prep: bf16 weights + combined (mask + gathered rel-pos bias) table ----
// ws layout: [0, 131072) bytes: qkv_w bf16 (49152 sh) then proj_w bf16 (16384 sh)
//            [131072, ...): cm3 fp32 MFMA-C-tiled [w][h][mt][nt][lane][r]
//                           = 64*4*4*4*64*4 floats = 4,194,304 B
//            element (row = mt*16 + (lane>>4)*4 + r, col = nt*16 + (lane&15));
//            rows >= 49 replicate row 48; cols >= 49 hold -1e30 (pad baked in)
__global__ __launch_bounds__(256) void prep_kernel(
    const float* __restrict__ qkv_w, const float* __restrict__ proj_w,
    const float* __restrict__ bias_table, const float* __restrict__ mask,
    unsigned short* __restrict__ wbf, float* __restrict__ cm3)
{
    int g = blockIdx.x * 256 + threadIdx.x;
    if (g < 49152) {
        wbf[g] = f2bf(qkv_w[g]);
    } else if (g < 65536) {
        wbf[g] = f2bf(proj_w[g - 49152]);
    } else if (g < 1114112) {
        int t = g - 65536;              // ((((w*4+h)*4+mt)*4+nt)*64+lane)*4+r
        int r    = t & 3;
        int lane = (t >> 2) & 63;
        int nt   = (t >> 8) & 3;
        int mt   = (t >> 10) & 3;
        int wh   = t >> 12;             // w*4 + h
        int h    = wh & 3;
        int w    = wh >> 2;
        int row  = mt * 16 + (lane >> 4) * 4 + r;
        int col  = nt * 16 + (lane & 15);
        int rowc = (row < 49) ? row : 48;
        float v;
        if (col < 49) {
            int idx = (rowc / 7 - col / 7 + 6) * 13 + (rowc % 7 - col % 7 + 6);
            v = mask[w * 2401 + rowc * 49 + col] + bias_table[idx * 4 + h];
        } else {
            v = -1e30f;
        }
        cm3[t] = v;
    }
}

// 512 threads = 8 waves; wave = (h = wid>>1, half = wid&1).
// ROW-SPLIT: wave (h,half) owns output rows [32*half, 32*half+32) throughout:
//   QKV: its 2 M-tiles x all 32 cols of head h (6 col-tiles of 16) -> ax[2][4]
//   S/softmax/PV/proj: rows mt in {2half, 2half+1}.
// Mask+bias fused as S-MFMA C operand (cm3 preloaded into sacc).
//
// LDS map (shorts). Head h region base hq = h*6528 (13056 B):
//   q:  hq+0     64 rows x 34  (2176)     [dead after S frag loads — see barrier]
//   k:  hq+2176  64 rows x 34  (2176)     [dead after S frag loads]
//   vT: hq+4352  32 rows x 68  (2176)
//   P:  hq+0     64 rows x 68  (4352)     [overlaps dead q+k exactly; RACE NOTE:
//       k rows are read across the wave pair, so a barrier separates the pair's
//       aq/bk ds_reads from P-writes — placed right after the S MFMAs]
// xs/ao: offset 0, 64 rows x 136 (8704)   [time-sliced vs head regions, barriers]
// total 26112 shorts = 52224 B -> 3 blocks/CU = 24 waves/CU (6 waves/SIMD)
__global__ __launch_bounds__(512, 6) void winattn_mfma(
    const float* __restrict__ x,
    const float* __restrict__ qkv_b,
    const float* __restrict__ proj_b,
    const unsigned short* __restrict__ wbf,
    const float* __restrict__ cm3,
    float* __restrict__ out)
{
    __shared__ __align__(16) short smem[26112];   // 52224 B

    const int tid  = threadIdx.x;
    const int lane = tid & 63;
    const int lid  = lane & 15;
    const int quad = lane >> 4;
    const int wid  = tid >> 6;        // 0..7
    const int h    = wid >> 1;        // head
    const int half = wid & 1;         // row-half owner
    const int b    = blockIdx.x;
    const int w    = b & 63;
    const int hq   = h * 6528;

    // ---- Phase 0: stage x (49x128) fp32 -> bf16 LDS rows (pitch 136), pad rows zeroed ----
    {
        const float4* xg = (const float4*)(x + (size_t)b * 6272);
        for (int i = tid; i < 1568; i += 512) {       // 49*32 float4s
            int n = i >> 5, c4 = i & 31;
            float4 v = xg[i];
            ushort4 u;
            u.x = f2bf(v.x); u.y = f2bf(v.y); u.z = f2bf(v.z); u.w = f2bf(v.w);
            *(ushort4*)&smem[n * 136 + c4 * 4] = u;
        }
        ushort4 z; z.x = 0; z.y = 0; z.z = 0; z.w = 0;
        for (int i = tid; i < 510; i += 512)          // rows 49..63: 15*136/4 = 510
            *(ushort4*)&smem[49 * 136 + i * 4] = z;
    }
    __syncthreads();

    // ---- load OWN A-tile rows (32x128) into registers: 8 frags (32 VGPR) ----
    bf16x8 ax[2][4];
    #pragma unroll
    for (int m = 0; m < 2; ++m)
        #pragma unroll
        for (int kb = 0; kb < 4; ++kb)
            ax[m][kb] = *(const bf16x8*)&smem[((2 * half + m) * 16 + lid) * 136 + kb * 32 + quad * 8];
    __syncthreads();   // xs consumed; head regions may now be written

    const floatx4 z4 = {0.f, 0.f, 0.f, 0.f};

    // ---- QKV: wave (h,half) computes own 2 M-tiles x 6 col-tiles (48 MFMAs) ----
    #pragma unroll
    for (int j = 0; j < 6; ++j) {
        const int part = j >> 1;                       // 0=q, 1=k, 2=v
        const int c    = j & 1;                        // col sub-tile
        const int cb   = part * 128 + h * 32 + c * 16;
        const unsigned short* wr = wbf + (size_t)(cb + lid) * 128 + quad * 8;
        floatx4 acc[2] = {z4, z4};
        #pragma unroll
        for (int kb = 0; kb < 4; ++kb) {
            bf16x8 bw = *(const bf16x8*)(wr + kb * 32);
            #pragma unroll
            for (int m = 0; m < 2; ++m)
                acc[m] = __builtin_amdgcn_mfma_f32_16x16x32_bf16(ax[m][kb], bw, acc[m], 0, 0, 0);
        }
        const float bias = qkv_b[cb + lid];
        #pragma unroll
        for (int m = 0; m < 2; ++m) {
            #pragma unroll
            for (int r = 0; r < 4; ++r) {
                const int row = (2 * half + m) * 16 + quad * 4 + r;
                const float v = acc[m][r] + bias;
                if (part == 0) {        // q (pre-scaled), pitch 34
                    smem[hq + row * 34 + c * 16 + lid] = (short)f2bf(v * QK_SCALE);
                } else if (part == 1) { // k row-major, pitch 34
                    smem[hq + 2176 + row * 34 + c * 16 + lid] = (short)f2bf(v);
                } else {                // v transposed: vT[d][token], pitch 68
                    smem[hq + 4352 + (c * 16 + lid) * 68 + row] = (short)f2bf(v);
                }
            }
        }
    }
    __syncthreads();   // k rows + vT token-cols cross the wave pair

    // ---- preload mask+bias tiles as S-MFMA C operands (8 coalesced float4) ----
    // Issued before the aq/bk ds_reads so L2 latency hides under them.
    floatx4 sacc[2][4];
    const floatx4* cm3b = (const floatx4*)cm3 + (size_t)((w * 4 + h) * 16) * 64 + lane;
    #pragma unroll
    for (int m = 0; m < 2; ++m)
        #pragma unroll
        for (int nt = 0; nt < 4; ++nt)
            sacc[m][nt] = cm3b[((2 * half + m) * 4 + nt) * 64];

    // ---- S = q @ k^T + cm : own 2 M-tiles x 4 N-tiles (8 MFMAs) ----
    bf16x8 aq[2], bk[4];
    #pragma unroll
    for (int m = 0; m < 2; ++m)
        aq[m] = ld8_4x2(&smem[hq + ((2 * half + m) * 16 + lid) * 34 + quad * 8]);
    #pragma unroll
    for (int nt = 0; nt < 4; ++nt)
        bk[nt] = ld8_4x2(&smem[hq + 2176 + (nt * 16 + lid) * 34 + quad * 8]);

    #pragma unroll
    for (int m = 0; m < 2; ++m)
        #pragma unroll
        for (int nt = 0; nt < 4; ++nt)
            sacc[m][nt] = __builtin_amdgcn_mfma_f32_16x16x32_bf16(aq[m], bk[nt], sacc[m][nt], 0, 0, 0);

    // Both waves of the pair must finish their aq/bk ds_reads before either
    // overwrites q/k with P (P overlays q+k). Barrier here closes the race.
    __syncthreads();

    // ---- softmax in C-layout; write P (bf16, pitch 68) into dead q/k region ----
    // cm3 already added by MFMA (pad cols hold -1e30), so sv is sacc directly.
    float invs[2][4];
    #pragma unroll
    for (int m = 0; m < 2; ++m) {
        #pragma unroll
        for (int r = 0; r < 4; ++r) {
            const int row = (2 * half + m) * 16 + quad * 4 + r;
            float sv[4];
            #pragma unroll
            for (int nt = 0; nt < 4; ++nt)
                sv[nt] = sacc[m][nt][r];
            float mx = fmaxf(fmaxf(sv[0], sv[1]), fmaxf(sv[2], sv[3]));
            #pragma unroll
            for (int d = 1; d < 16; d <<= 1) mx = fmaxf(mx, __shfl_xor(mx, d));
            float sum = 0.f;
            #pragma unroll
            for (int nt = 0; nt < 4; ++nt) { float p = __expf(sv[nt] - mx); sv[nt] = p; sum += p; }
            #pragma unroll
            for (int d = 1; d < 16; d <<= 1) sum += __shfl_xor(sum, d);
            invs[m][r] = 1.f / sum;
            #pragma unroll
            for (int nt = 0; nt < 4; ++nt)
                smem[hq + row * 68 + nt * 16 + lid] = (short)f2bf(sv[nt]);
        }
    }

    // ---- O = P @ v : own 2 M-tiles (8 MFMAs), scale rows by 1/sum ----
    bf16x8 bv[2][2];
    #pragma unroll
    for (int nt2 = 0; nt2 < 2; ++nt2)
        #pragma unroll
        for (int kb2 = 0; kb2 < 2; ++kb2)
            bv[nt2][kb2] = ld8_2x4(&smem[hq + 4352 + (nt2 * 16 + lid) * 68 + kb2 * 32 + quad * 8]);

    floatx4 oacc[2][2] = {{z4, z4}, {z4, z4}};
    #pragma unroll
    for (int m = 0; m < 2; ++m) {
        #pragma unroll
        for (int kb2 = 0; kb2 < 2; ++kb2) {
            bf16x8 ap = ld8_2x4(&smem[hq + ((2 * half + m) * 16 + lid) * 68 + kb2 * 32 + quad * 8]);
            #pragma unroll
            for (int nt2 = 0; nt2 < 2; ++nt2)
                oacc[m][nt2] = __builtin_amdgcn_mfma_f32_16x16x32_bf16(ap, bv[nt2][kb2], oacc[m][nt2], 0, 0, 0);
        }
    }

    __syncthreads();   // all O MFMAs done everywhere; P/vT/q/k dead -> ao may overwrite

    // ---- write attn-out (bf16) to ao (pitch 136, offset 0), own rows ----
    #pragma unroll
    for (int m = 0; m < 2; ++m)
        #pragma unroll
        for (int nt2 = 0; nt2 < 2; ++nt2)
            #pragma unroll
            for (int r = 0; r < 4; ++r) {
                const int row = (2 * half + m) * 16 + quad * 4 + r;
                smem[row * 136 + h * 32 + nt2 * 16 + lid] =
                    (short)f2bf(oacc[m][nt2][r] * invs[m][r]);
            }
    __syncthreads();

    // ---- proj: C2 = ao @ proj_w.T ; wave (h,half) -> cols [32h,32h+32) x own rows ----
    bf16x8 aa[2][4];
    #pragma unroll
    for (int m = 0; m < 2; ++m)
        #pragma unroll
        for (int kb = 0; kb < 4; ++kb)
            aa[m][kb] = *(const bf16x8*)&smem[((2 * half + m) * 16 + lid) * 136 + kb * 32 + quad * 8];

    float* outb = out + (size_t)b * 6272;
    #pragma unroll
    for (int nt = 0; nt < 2; ++nt) {
        const int cb = h * 32 + nt * 16;
        const unsigned short* wr = wbf + 49152 + (size_t)(cb + lid) * 128 + quad * 8;
        floatx4 acc[2] = {z4, z4};
        #pragma unroll
        for (int kb = 0; kb < 4; ++kb) {
            bf16x8 bw = *(const bf16x8*)(wr + kb * 32);
            #pragma unroll
            for (int m = 0; m < 2; ++m)
                acc[m] = __builtin_amdgcn_mfma_f32_16x16x32_bf16(aa[m][kb], bw, acc[m], 0, 0, 0);
        }
        const float pb = proj_b[cb + lid];
        #pragma unroll
        for (int m = 0; m < 2; ++m)
            #pragma unroll
            for (int r = 0; r < 4; ++r) {
                const int row = (2 * half + m) * 16 + quad * 4 + r;
                if (row < 49)
                    outb[row * 128 + cb + lid] = acc[m][r] + pb;
            }
    }
}

extern "C" void kernel_launch(void* const* d_in, const int* in_sizes, int n_in,
                              void* d_out, int out_size, void* d_ws, size_t ws_size,
                              hipStream_t stream) {
    (void)in_sizes; (void)n_in; (void)out_size; (void)ws_size;
    const float* x          = (const float*)d_in[0];
    const float* mask       = (const float*)d_in[1];
    const float* qkv_w      = (const float*)d_in[2];
    const float* qkv_b      = (const float*)d_in[3];
    const float* proj_w     = (const float*)d_in[4];
    const float* proj_b     = (const float*)d_in[5];
    const float* bias_table = (const float*)d_in[6];

    unsigned short* wbf = (unsigned short*)d_ws;                 // 131072 B
    float* cm3          = (float*)((char*)d_ws + 131072);        // 4,194,304 B

    prep_kernel<<<4352, 256, 0, stream>>>(qkv_w, proj_w, bias_table, mask, wbf, cm3);
    winattn_mfma<<<4096, 512, 0, stream>>>(x, qkv_b, proj_b, wbf, cm3, (float*)d_out);
}

// Round 8
// 270.082 us; speedup vs baseline: 1.7650x; 1.1542x over previous
//
#include <hip/hip_runtime.h>

#define QK_SCALE 0.17677669529663687f

typedef __attribute__((ext_vector_type(8))) short bf16x8;
typedef __attribute__((ext_vector_type(4))) short bf16x4;
typedef __attribute__((ext_vector_type(2))) short bf16x2;
typedef __attribute__((ext_vector_type(4))) float floatx4;

__device__ __forceinline__ unsigned short f2bf(float f) {
    unsigned int u = __float_as_uint(f);
    u += 0x7fffu + ((u >> 16) & 1u);   // round-to-nearest-even
    return (unsigned short)(u >> 16);
}

__device__ __forceinline__ bf16x8 ld8_2x4(const short* p) {  // 8B-aligned pair load
    union { bf16x8 v8; bf16x4 v4[2]; } u;
    u.v4[0] = *(const bf16x4*)p;
    u.v4[1] = *(const bf16x4*)(p + 4);
    return u.v8;
}

__device__ __forceinline__ bf16x8 ld8_4x2(const short* p) {  // 4B-aligned quad load
    union { bf16x8 v8; bf16x2 v2[4]; } u;
    u.v2[0] = *(const bf16x2*)p;
    u.v2[1] = *(const bf16x2*)(p + 2);
    u.v2[2] = *(const bf16x2*)(p + 4);
    u.v2[3] = *(const bf16x2*)(p + 6);
    return u.v8;
}

// ---- prep: bf16 weights + combined (mask + gathered rel-pos bias) table ----
// ws layout: [0, 131072) bytes: qkv_w bf16 (49152 sh) then proj_w bf16 (16384 sh)
//            [131072, ...): cm3 fp32 MFMA-C-tiled [w][h][mt][nt][lane][r]
//                           = 64*4*4*4*64*4 floats = 4,194,304 B
//            element (row = mt*16 + (lane>>4)*4 + r, col = nt*16 + (lane&15));
//            rows >= 49 replicate row 48; cols >= 49 hold -1e30 (pad baked in)
__global__ __launch_bounds__(256) void prep_kernel(
    const float* __restrict__ qkv_w, const float* __restrict__ proj_w,
    const float* __restrict__ bias_table, const float* __restrict__ mask,
    unsigned short* __restrict__ wbf, float* __restrict__ cm3)
{
    int g = blockIdx.x * 256 + threadIdx.x;
    if (g < 49152) {
        wbf[g] = f2bf(qkv_w[g]);
    } else if (g < 65536) {
        wbf[g] = f2bf(proj_w[g - 49152]);
    } else if (g < 1114112) {
        int t = g - 65536;              // ((((w*4+h)*4+mt)*4+nt)*64+lane)*4+r
        int r    = t & 3;
        int lane = (t >> 2) & 63;
        int nt   = (t >> 8) & 3;
        int mt   = (t >> 10) & 3;
        int wh   = t >> 12;             // w*4 + h
        int h    = wh & 3;
        int w    = wh >> 2;
        int row  = mt * 16 + (lane >> 4) * 4 + r;
        int col  = nt * 16 + (lane & 15);
        int rowc = (row < 49) ? row : 48;
        float v;
        if (col < 49) {
            int idx = (rowc / 7 - col / 7 + 6) * 13 + (rowc % 7 - col % 7 + 6);
            v = mask[w * 2401 + rowc * 49 + col] + bias_table[idx * 4 + h];
        } else {
            v = -1e30f;
        }
        cm3[t] = v;
    }
}

// 256 threads = 4 waves; wave = head (proven 143 us operating point).
// Per-wave latency cuts vs round-2 base:
//   (1) mask+bias fused as S-MFMA C operand (cm3 preload -> sacc),
//   (2) QKV weight loads 2-stage software-pipelined (prefetch t+1 during t),
//   (3) proj weights prefetched right after PV MFMAs.
//
// LDS map (shorts). Head h region base hq = h*6528 (13056 B):
//   q:  hq+0     64 rows x 34  (2176)     [dead after S frag loads; wave-private]
//   k:  hq+2176  64 rows x 34  (2176)     [dead after S frag loads; wave-private]
//   vT: hq+4352  32 rows x 68  (2176)
//   P:  hq+0     64 rows x 68  (4352)     [overlaps dead q+k; same-wave in-order LDS]
// xs/ao: offset 0, 64 rows x 136 (8704)   [time-sliced vs head regions, barriers]
// total 26112 shorts = 52224 B -> 3 blocks/CU = 12 waves/CU (3 waves/SIMD)
__global__ __launch_bounds__(256, 3) void winattn_mfma(
    const float* __restrict__ x,
    const float* __restrict__ qkv_b,
    const float* __restrict__ proj_b,
    const unsigned short* __restrict__ wbf,
    const float* __restrict__ cm3,
    float* __restrict__ out)
{
    __shared__ __align__(16) short smem[26112];   // 52224 B

    const int tid  = threadIdx.x;
    const int lane = tid & 63;
    const int lid  = lane & 15;
    const int quad = lane >> 4;
    const int h    = tid >> 6;        // wave = head
    const int b    = blockIdx.x;
    const int w    = b & 63;
    const int hq   = h * 6528;

    // ---- Phase 0: stage x (49x128) fp32 -> bf16 LDS rows (pitch 136), pad rows zeroed ----
    {
        const float4* xg = (const float4*)(x + (size_t)b * 6272);
        for (int i = tid; i < 1568; i += 256) {       // 49*32 float4s
            int n = i >> 5, c4 = i & 31;
            float4 v = xg[i];
            ushort4 u;
            u.x = f2bf(v.x); u.y = f2bf(v.y); u.z = f2bf(v.z); u.w = f2bf(v.w);
            *(ushort4*)&smem[n * 136 + c4 * 4] = u;
        }
        ushort4 z; z.x = 0; z.y = 0; z.z = 0; z.w = 0;
        for (int i = tid; i < 510; i += 256)          // rows 49..63: 15*136/4 = 510
            *(ushort4*)&smem[49 * 136 + i * 4] = z;
    }
    __syncthreads();

    // ---- load full A tile (64x128) into registers: 16 frags ----
    bf16x8 ax[4][4];
    #pragma unroll
    for (int mt = 0; mt < 4; ++mt)
        #pragma unroll
        for (int kb = 0; kb < 4; ++kb)
            ax[mt][kb] = *(const bf16x8*)&smem[(mt * 16 + lid) * 136 + kb * 32 + quad * 8];
    __syncthreads();   // xs consumed; head regions may now be written

    const floatx4 z4 = {0.f, 0.f, 0.f, 0.f};

    // ---- QKV: wave h computes q,k,v cols [32h,32h+32): 6 tiles, bw prefetched ----
    bf16x8 bwc[4], bwn[4];
    {
        const unsigned short* wr0 = wbf + (size_t)(h * 32 + lid) * 128 + quad * 8;
        #pragma unroll
        for (int kb = 0; kb < 4; ++kb)
            bwc[kb] = *(const bf16x8*)(wr0 + kb * 32);
    }
    #pragma unroll
    for (int t = 0; t < 6; ++t) {
        const int part = t >> 1;                       // 0=q, 1=k, 2=v
        const int c    = t & 1;                        // col sub-tile
        const int cb   = part * 128 + h * 32 + c * 16;
        if (t < 5) {   // prefetch next tile's weights while this tile computes
            const int tn = t + 1;
            const int cbn = (tn >> 1) * 128 + h * 32 + (tn & 1) * 16;
            const unsigned short* wrn = wbf + (size_t)(cbn + lid) * 128 + quad * 8;
            #pragma unroll
            for (int kb = 0; kb < 4; ++kb)
                bwn[kb] = *(const bf16x8*)(wrn + kb * 32);
        }
        floatx4 acc[4] = {z4, z4, z4, z4};
        #pragma unroll
        for (int kb = 0; kb < 4; ++kb)
            #pragma unroll
            for (int mt = 0; mt < 4; ++mt)
                acc[mt] = __builtin_amdgcn_mfma_f32_16x16x32_bf16(ax[mt][kb], bwc[kb], acc[mt], 0, 0, 0);
        const float bias = qkv_b[cb + lid];
        #pragma unroll
        for (int mt = 0; mt < 4; ++mt) {
            #pragma unroll
            for (int r = 0; r < 4; ++r) {
                const int row = mt * 16 + quad * 4 + r;
                const float v = acc[mt][r] + bias;
                if (part == 0) {        // q (pre-scaled), pitch 34
                    smem[hq + row * 34 + c * 16 + lid] = (short)f2bf(v * QK_SCALE);
                } else if (part == 1) { // k row-major, pitch 34
                    smem[hq + 2176 + row * 34 + c * 16 + lid] = (short)f2bf(v);
                } else {                // v transposed: vT[d][token], pitch 68
                    smem[hq + 4352 + (c * 16 + lid) * 68 + row] = (short)f2bf(v);
                }
            }
        }
        #pragma unroll
        for (int kb = 0; kb < 4; ++kb) bwc[kb] = bwn[kb];
    }

    // ---- preload mask+bias tiles as S-MFMA C operands (16 coalesced float4) ----
    // Issued before the aq/bk ds_reads; L2 latency hides under LDS traffic.
    floatx4 sacc[4][4];
    const floatx4* cm3b = (const floatx4*)cm3 + (size_t)((w * 4 + h) * 16) * 64 + lane;
    #pragma unroll
    for (int mt = 0; mt < 4; ++mt)
        #pragma unroll
        for (int nt = 0; nt < 4; ++nt)
            sacc[mt][nt] = cm3b[(mt * 4 + nt) * 64];

    // ---- S = q @ k^T + cm : 16 MFMAs (wave-private q/k; in-order LDS per wave) ----
    bf16x8 aq[4], bk[4];
    #pragma unroll
    for (int mt = 0; mt < 4; ++mt)
        aq[mt] = ld8_4x2(&smem[hq + (mt * 16 + lid) * 34 + quad * 8]);
    #pragma unroll
    for (int nt = 0; nt < 4; ++nt)
        bk[nt] = ld8_4x2(&smem[hq + 2176 + (nt * 16 + lid) * 34 + quad * 8]);

    #pragma unroll
    for (int mt = 0; mt < 4; ++mt)
        #pragma unroll
        for (int nt = 0; nt < 4; ++nt)
            sacc[mt][nt] = __builtin_amdgcn_mfma_f32_16x16x32_bf16(aq[mt], bk[nt], sacc[mt][nt], 0, 0, 0);

    // ---- softmax in C-layout; write P (bf16, pitch 68) into dead q/k region ----
    // cm3 already added by MFMA (pad cols hold -1e30): sv is sacc directly.
    float invs[4][4];
    #pragma unroll
    for (int mt = 0; mt < 4; ++mt) {
        #pragma unroll
        for (int r = 0; r < 4; ++r) {
            const int row = mt * 16 + quad * 4 + r;
            float sv[4];
            #pragma unroll
            for (int nt = 0; nt < 4; ++nt)
                sv[nt] = sacc[mt][nt][r];
            float mx = fmaxf(fmaxf(sv[0], sv[1]), fmaxf(sv[2], sv[3]));
            #pragma unroll
            for (int d = 1; d < 16; d <<= 1) mx = fmaxf(mx, __shfl_xor(mx, d));
            float sum = 0.f;
            #pragma unroll
            for (int nt = 0; nt < 4; ++nt) { float p = __expf(sv[nt] - mx); sv[nt] = p; sum += p; }
            #pragma unroll
            for (int d = 1; d < 16; d <<= 1) sum += __shfl_xor(sum, d);
            invs[mt][r] = 1.f / sum;
            #pragma unroll
            for (int nt = 0; nt < 4; ++nt)
                smem[hq + row * 68 + nt * 16 + lid] = (short)f2bf(sv[nt]);
        }
    }

    // ---- O = P @ v  (16 MFMAs), scale rows by 1/sum ----
    bf16x8 bv[2][2];
    #pragma unroll
    for (int nt2 = 0; nt2 < 2; ++nt2)
        #pragma unroll
        for (int kb2 = 0; kb2 < 2; ++kb2)
            bv[nt2][kb2] = ld8_2x4(&smem[hq + 4352 + (nt2 * 16 + lid) * 68 + kb2 * 32 + quad * 8]);

    floatx4 oacc[4][2] = {{z4, z4}, {z4, z4}, {z4, z4}, {z4, z4}};
    #pragma unroll
    for (int mt = 0; mt < 4; ++mt) {
        #pragma unroll
        for (int kb2 = 0; kb2 < 2; ++kb2) {
            bf16x8 ap = ld8_2x4(&smem[hq + (mt * 16 + lid) * 68 + kb2 * 32 + quad * 8]);
            #pragma unroll
            for (int nt2 = 0; nt2 < 2; ++nt2)
                oacc[mt][nt2] = __builtin_amdgcn_mfma_f32_16x16x32_bf16(ap, bv[nt2][kb2], oacc[mt][nt2], 0, 0, 0);
        }
    }

    // ---- prefetch proj weights (8 frags); latency hides under barriers+ao+aa ----
    bf16x8 pw[2][4];
    #pragma unroll
    for (int nt = 0; nt < 2; ++nt) {
        const unsigned short* wr = wbf + 49152 + (size_t)(h * 32 + nt * 16 + lid) * 128 + quad * 8;
        #pragma unroll
        for (int kb = 0; kb < 4; ++kb)
            pw[nt][kb] = *(const bf16x8*)(wr + kb * 32);
    }

    __syncthreads();   // all O MFMAs done everywhere; P/vT/q/k dead -> ao may overwrite

    // ---- write attn-out (bf16) to ao (pitch 136, offset 0) ----
    #pragma unroll
    for (int mt = 0; mt < 4; ++mt)
        #pragma unroll
        for (int nt2 = 0; nt2 < 2; ++nt2)
            #pragma unroll
            for (int r = 0; r < 4; ++r) {
                const int row = mt * 16 + quad * 4 + r;
                smem[row * 136 + h * 32 + nt2 * 16 + lid] =
                    (short)f2bf(oacc[mt][nt2][r] * invs[mt][r]);
            }
    __syncthreads();

    // ---- proj: C2 = ao @ proj_w.T ; wave h -> cols [32h, 32h+32) ----
    bf16x8 aa[4][4];
    #pragma unroll
    for (int mt = 0; mt < 4; ++mt)
        #pragma unroll
        for (int kb = 0; kb < 4; ++kb)
            aa[mt][kb] = *(const bf16x8*)&smem[(mt * 16 + lid) * 136 + kb * 32 + quad * 8];

    float* outb = out + (size_t)b * 6272;
    #pragma unroll
    for (int nt = 0; nt < 2; ++nt) {
        const int cb = h * 32 + nt * 16;
        floatx4 acc[4] = {z4, z4, z4, z4};
        #pragma unroll
        for (int kb = 0; kb < 4; ++kb)
            #pragma unroll
            for (int mt = 0; mt < 4; ++mt)
                acc[mt] = __builtin_amdgcn_mfma_f32_16x16x32_bf16(aa[mt][kb], pw[nt][kb], acc[mt], 0, 0, 0);
        const float pb = proj_b[cb + lid];
        #pragma unroll
        for (int mt = 0; mt < 4; ++mt)
            #pragma unroll
            for (int r = 0; r < 4; ++r) {
                const int row = mt * 16 + quad * 4 + r;
                if (row < 49)
                    outb[row * 128 + cb + lid] = acc[mt][r] + pb;
            }
    }
}

extern "C" void kernel_launch(void* const* d_in, const int* in_sizes, int n_in,
                              void* d_out, int out_size, void* d_ws, size_t ws_size,
                              hipStream_t stream) {
    (void)in_sizes; (void)n_in; (void)out_size; (void)ws_size;
    const float* x          = (const float*)d_in[0];
    const float* mask       = (const float*)d_in[1];
    const float* qkv_w      = (const float*)d_in[2];
    const float* qkv_b      = (const float*)d_in[3];
    const float* proj_w     = (const float*)d_in[4];
    const float* proj_b     = (const float*)d_in[5];
    const float* bias_table = (const float*)d_in[6];

    unsigned short* wbf = (unsigned short*)d_ws;                 // 131072 B
    float* cm3          = (float*)((char*)d_ws + 131072);        // 4,194,304 B

    prep_kernel<<<4352, 256, 0, stream>>>(qkv_w, proj_w, bias_table, mask, wbf, cm3);
    winattn_mfma<<<4096, 256, 0, stream>>>(x, qkv_b, proj_b, wbf, cm3, (float*)d_out);
}